// Round 2
// baseline (505.057 us; speedup 1.0000x reference)
//
#include <hip/hip_runtime.h>
#include <hip/hip_bf16.h>

typedef float f32x4 __attribute__((ext_vector_type(4)));
typedef short bf16x8 __attribute__((ext_vector_type(8)));

#define MFMA_BF16 __builtin_amdgcn_mfma_f32_16x16x32_bf16

static __device__ __forceinline__ unsigned short f2bf(float f) {
    __hip_bfloat16 h = __float2bfloat16(f);
    return __builtin_bit_cast(unsigned short, h);
}
static __device__ __forceinline__ unsigned int pack2(float a, float b) {
    return (unsigned int)f2bf(a) | ((unsigned int)f2bf(b) << 16);
}

// Async global->LDS, 16B per lane. LDS dest is wave-uniform base + lane*16.
static __device__ __forceinline__ void gl16(const unsigned short* g, unsigned short* l) {
    unsigned short* gg = const_cast<unsigned short*>(g);
    __builtin_amdgcn_global_load_lds(
        (__attribute__((address_space(1))) unsigned int*)gg,
        (__attribute__((address_space(3))) unsigned int*)l, 16, 0, 0);
}

// ---------------------------------------------------------------------------
// Prep 1: W [1024][1024] f32 (k-major) -> Wt [1024][1024] bf16 (n-major, k-contig)
// 64x64 tiles via LDS. grid (16,16,4): z selects Wq/Wk/Wv/Wo.
// ---------------------------------------------------------------------------
__global__ __launch_bounds__(256) void conv_wT(
    const float* __restrict__ Wq, const float* __restrict__ Wk,
    const float* __restrict__ Wv, const float* __restrict__ Wo,
    unsigned short* __restrict__ WT)
{
    const int z = blockIdx.z;
    const float* W = (z == 0) ? Wq : (z == 1) ? Wk : (z == 2) ? Wv : Wo;
    unsigned short* Wt = WT + (size_t)z * 1048576;
    const int k0 = blockIdx.x * 64, n0 = blockIdx.y * 64;
    __shared__ float tl[64][68];
    const int t = threadIdx.x;
    const int r = t >> 2, cs = (t & 3) * 16;
#pragma unroll
    for (int j = 0; j < 4; j++)
        *(float4*)&tl[r][cs + j * 4] = *(const float4*)&W[(size_t)(k0 + r) * 1024 + n0 + cs + j * 4];
    __syncthreads();
    const int n = t & 63, kb = (t >> 6) * 16;
#pragma unroll
    for (int j = 0; j < 4; j++) {
        const int kk = kb + j * 4;
        uint2 o = { pack2(tl[kk][n], tl[kk + 1][n]), pack2(tl[kk + 2][n], tl[kk + 3][n]) };
        *(uint2*)&Wt[(size_t)(n0 + n) * 1024 + k0 + kk] = o;
    }
}

// ---------------------------------------------------------------------------
// Prep 2: q/k/v f32 -> bf16. grid (2048, 3).
// ---------------------------------------------------------------------------
__global__ __launch_bounds__(256) void conv_bf16(
    const float* __restrict__ q, const float* __restrict__ k, const float* __restrict__ v,
    unsigned short* __restrict__ qkvb)
{
    const int z = blockIdx.y;
    const float* s = (z == 0) ? q : (z == 1) ? k : v;
    unsigned short* d = qkvb + (size_t)z * 4194304;
    const size_t i = ((size_t)blockIdx.x * 256 + threadIdx.x) * 8;
    float4 a = *(const float4*)&s[i], b = *(const float4*)&s[i + 4];
    uint4 o = { pack2(a.x, a.y), pack2(a.z, a.w), pack2(b.x, b.y), pack2(b.z, b.w) };
    *(uint4*)&d[i] = o;
}

// ---------------------------------------------------------------------------
// Shared GEMM core: C(128x128) = A(row-major [M][1024] bf16) x Bt^T
// (Bt row-major [N][1024] bf16), global_load_lds staging, BK=32, 4 waves 2x2.
// ---------------------------------------------------------------------------
static __device__ __forceinline__ void gemm_core(
    const unsigned short* __restrict__ A, const unsigned short* __restrict__ Bt,
    unsigned short* lA, unsigned short* lB, int m0, int n0, f32x4 (&acc)[4][4])
{
    const int t = threadIdx.x;
    const int w = t >> 6, lane = t & 63, lrow = lane & 15, lkg = lane >> 4;
    const int wr = w >> 1, wc = w & 1;
    const int srow = lane >> 2, sseg = (lane & 3) * 8;

    for (int k0 = 0; k0 < 1024; k0 += 32) {
        gl16(&A[(size_t)(m0 + w * 32 + srow) * 1024 + k0 + sseg], &lA[w * 1024]);
        gl16(&A[(size_t)(m0 + w * 32 + 16 + srow) * 1024 + k0 + sseg], &lA[w * 1024 + 512]);
        gl16(&Bt[(size_t)(n0 + w * 32 + srow) * 1024 + k0 + sseg], &lB[w * 1024]);
        gl16(&Bt[(size_t)(n0 + w * 32 + 16 + srow) * 1024 + k0 + sseg], &lB[w * 1024 + 512]);
        __syncthreads();
        bf16x8 af[4], bfr[4];
#pragma unroll
        for (int mi = 0; mi < 4; mi++)
            af[mi] = *(const bf16x8*)&lA[(wr * 64 + mi * 16 + lrow) * 32 + lkg * 8];
#pragma unroll
        for (int ni = 0; ni < 4; ni++)
            bfr[ni] = *(const bf16x8*)&lB[(wc * 64 + ni * 16 + lrow) * 32 + lkg * 8];
#pragma unroll
        for (int mi = 0; mi < 4; mi++)
#pragma unroll
            for (int ni = 0; ni < 4; ni++)
                acc[mi][ni] = MFMA_BF16(af[mi], bfr[ni], acc[mi][ni], 0, 0, 0);
        __syncthreads();
    }
}

// ---------------------------------------------------------------------------
// QKV projections. z=0: Q->[B,H,L,64]; z=1: K->[B,H,L,64]; z=2: V->[B,H,64,L].
// ---------------------------------------------------------------------------
__global__ __launch_bounds__(256) void gemm_qkv(
    const unsigned short* __restrict__ qkvb, const unsigned short* __restrict__ WT,
    const float* __restrict__ bq, const float* __restrict__ bk, const float* __restrict__ bv,
    unsigned short* __restrict__ Qh, unsigned short* __restrict__ Kh, unsigned short* __restrict__ Vt)
{
    const int z = blockIdx.z;
    const unsigned short* A = qkvb + (size_t)z * 4194304;
    const unsigned short* Bt = WT + (size_t)z * 1048576;
    const float* bias = (z == 0) ? bq : (z == 1) ? bk : bv;

    const int n0 = blockIdx.x * 128, m0 = blockIdx.y * 128;
    __shared__ unsigned short lA[4096], lB[4096];
    f32x4 acc[4][4];
#pragma unroll
    for (int i = 0; i < 4; i++)
#pragma unroll
        for (int j = 0; j < 4; j++) acc[i][j] = (f32x4){0.f, 0.f, 0.f, 0.f};

    gemm_core(A, Bt, lA, lB, m0, n0, acc);

    const int t = threadIdx.x;
    const int w = t >> 6, lane = t & 63, lrow = lane & 15, lkg = lane >> 4;
    const int wr = w >> 1, wc = w & 1;

#pragma unroll
    for (int mi = 0; mi < 4; mi++) {
#pragma unroll
        for (int ni = 0; ni < 4; ni++) {
            const int gn = n0 + wc * 64 + ni * 16 + lrow;
            const float bb = bias[gn];
            const int hh = gn >> 6, dk = gn & 63;
            const int gm0 = m0 + wr * 64 + mi * 16 + lkg * 4;
            const int b2 = gm0 >> 11, ll = gm0 & 2047;
            if (z < 2) {
                unsigned short* C = (z == 0) ? Qh : Kh;
#pragma unroll
                for (int r = 0; r < 4; r++)
                    C[(size_t)((b2 * 16 + hh) * 2048 + ll + r) * 64 + dk] = f2bf(acc[mi][ni][r] + bb);
            } else {
                uint2 o = { pack2(acc[mi][ni][0] + bb, acc[mi][ni][1] + bb),
                            pack2(acc[mi][ni][2] + bb, acc[mi][ni][3] + bb) };
                *(uint2*)&Vt[(size_t)((b2 * 16 + hh) * 64 + dk) * 2048 + ll] = o;
            }
        }
    }
}

// ---------------------------------------------------------------------------
// Output projection: out_f32 = Oh_bf16 @ WoT^T + bo.
// ---------------------------------------------------------------------------
__global__ __launch_bounds__(256) void gemm_o(
    const unsigned short* __restrict__ Oh, const unsigned short* __restrict__ WoT,
    const float* __restrict__ bo, float* __restrict__ out)
{
    const int n0 = blockIdx.x * 128, m0 = blockIdx.y * 128;
    __shared__ unsigned short lA[4096], lB[4096];
    f32x4 acc[4][4];
#pragma unroll
    for (int i = 0; i < 4; i++)
#pragma unroll
        for (int j = 0; j < 4; j++) acc[i][j] = (f32x4){0.f, 0.f, 0.f, 0.f};

    gemm_core(Oh, WoT, lA, lB, m0, n0, acc);

    const int t = threadIdx.x;
    const int w = t >> 6, lane = t & 63, lrow = lane & 15, lkg = lane >> 4;
    const int wr = w >> 1, wc = w & 1;

#pragma unroll
    for (int mi = 0; mi < 4; mi++) {
#pragma unroll
        for (int ni = 0; ni < 4; ni++) {
            const int gn = n0 + wc * 64 + ni * 16 + lrow;
            const float bb = bo[gn];
            const int gm0 = m0 + wr * 64 + mi * 16 + lkg * 4;
#pragma unroll
            for (int r = 0; r < 4; r++)
                out[(size_t)(gm0 + r) * 1024 + gn] = acc[mi][ni][r] + bb;
        }
    }
}

// ---------------------------------------------------------------------------
// Fused attention, barrier-free. 512 threads = 8 waves, wave owns 16 q-rows.
// Swapped QK^T: S^T = MFMA(K, Q) -> lane holds 4 consecutive k for one q-row.
// Sweep 1: denominators (no max: |S| < 5). Sweep 2: recompute S, write
// normalized attn (f32x4 stores) + PV via wave-private swizzled LDS P.
// K read direct from global (L1/L2-resident); V pre-transposed [B,H,64,L].
// ---------------------------------------------------------------------------
__global__ __launch_bounds__(512) void attn_kernel(
    const unsigned short* __restrict__ Qh, const unsigned short* __restrict__ Kh,
    const unsigned short* __restrict__ Vt, float* __restrict__ attn,
    unsigned short* __restrict__ Oh)
{
    // XCD-aware swizzle: 512 blocks, 64 contiguous logical blocks (4 bh) per XCD
    const int bid = blockIdx.x;
    const int swz = (bid & 7) * 64 + (bid >> 3);
    const int bh = swz >> 4;
    const int q0 = (swz & 15) * 128;
    const int b = bh >> 4, h = bh & 15;
    const int t = threadIdx.x;
    const int w = t >> 6, lane = t & 63, ql = lane & 15, kg = lane >> 4;

    __shared__ unsigned short lP[8 * 2048];   // per-wave [16 q][128 k], XOR-swizzled

    const size_t kvbase = (size_t)bh * 2048 * 64;
    const float scale = 0.125f;

    const unsigned short* qptr = Qh + kvbase + (size_t)(q0 + w * 16 + ql) * 64 + kg * 8;
    const bf16x8 qf0 = *(const bf16x8*)(qptr);
    const bf16x8 qf1 = *(const bf16x8*)(qptr + 32);

    const unsigned short* Kbh = Kh + kvbase;
    const unsigned short* Vbh = Vt + kvbase;  // same stride: 64*2048

    // ---- sweep 1: denominators ----
    float lsum = 0.f;
    for (int kt = 0; kt < 16; ++kt) {
        const unsigned short* kp = Kbh + (size_t)(kt * 128 + ql) * 64 + kg * 8;
        f32x4 sacc[8];
#pragma unroll
        for (int ni = 0; ni < 8; ni++) {
            bf16x8 kf0 = *(const bf16x8*)(kp + ni * 1024);
            bf16x8 kf1 = *(const bf16x8*)(kp + ni * 1024 + 32);
            f32x4 s = (f32x4){0.f, 0.f, 0.f, 0.f};
            s = MFMA_BF16(kf0, qf0, s, 0, 0, 0);
            s = MFMA_BF16(kf1, qf1, s, 0, 0, 0);
            sacc[ni] = s;
        }
#pragma unroll
        for (int ni = 0; ni < 8; ni++)
#pragma unroll
            for (int r = 0; r < 4; r++)
                lsum += __expf(sacc[ni][r] * scale);
    }
    lsum += __shfl_xor(lsum, 16);
    lsum += __shfl_xor(lsum, 32);
    const float inv_l = 1.0f / lsum;

    // ---- sweep 2: attn write + PV ----
    f32x4 acco[4];
#pragma unroll
    for (int nv = 0; nv < 4; nv++) acco[nv] = (f32x4){0.f, 0.f, 0.f, 0.f};

    unsigned short* lPw = &lP[w * 2048];
    const int swz8 = (ql & 7) << 3;   // short-index XOR (16B-granular byte swizzle)
    float* arow = attn + ((size_t)bh * 2048 + q0 + w * 16 + ql) * 2048;

    for (int kt = 0; kt < 16; ++kt) {
        const int k0 = kt * 128;
        const unsigned short* kp = Kbh + (size_t)(k0 + ql) * 64 + kg * 8;
        f32x4 sacc[8];
#pragma unroll
        for (int ni = 0; ni < 8; ni++) {
            bf16x8 kf0 = *(const bf16x8*)(kp + ni * 1024);
            bf16x8 kf1 = *(const bf16x8*)(kp + ni * 1024 + 32);
            f32x4 s = (f32x4){0.f, 0.f, 0.f, 0.f};
            s = MFMA_BF16(kf0, qf0, s, 0, 0, 0);
            s = MFMA_BF16(kf1, qf1, s, 0, 0, 0);
            sacc[ni] = s;
        }
#pragma unroll
        for (int ni = 0; ni < 8; ni++) {
            f32x4 p;
#pragma unroll
            for (int r = 0; r < 4; r++) p[r] = __expf(sacc[ni][r] * scale) * inv_l;
            // wave-private LDS (no cross-wave sharing -> no barrier needed)
            uint2 pk = { pack2(p[0], p[1]), pack2(p[2], p[3]) };
            *(uint2*)&lPw[(ql * 128 + ni * 16 + kg * 4) ^ swz8] = pk;
            // normalized attention row, vectorized f32 store
            *(f32x4*)&arow[k0 + ni * 16 + kg * 4] = p;
        }
        // PV: O^T += V^T x P^T  (A = V^T rows dv, B = P^T cols q)
#pragma unroll
        for (int s = 0; s < 4; s++) {
            bf16x8 pf = *(const bf16x8*)&lPw[(ql * 128 + s * 32 + kg * 8) ^ swz8];
            const unsigned short* vp = Vbh + (size_t)ql * 2048 + k0 + s * 32 + kg * 8;
#pragma unroll
            for (int nv = 0; nv < 4; nv++) {
                bf16x8 vf = *(const bf16x8*)(vp + (size_t)nv * 16 * 2048);
                acco[nv] = MFMA_BF16(vf, pf, acco[nv], 0, 0, 0);
            }
        }
    }

    // O^T frag: lane holds q=ql, dv = nv*16 + kg*4 + r -> Oh [B,L,H*64] bf16
    unsigned short* obase = Oh + ((size_t)(b * 2048 + q0 + w * 16 + ql)) * 1024 + h * 64 + kg * 4;
#pragma unroll
    for (int nv = 0; nv < 4; nv++) {
        uint2 o2 = { pack2(acco[nv][0], acco[nv][1]), pack2(acco[nv][2], acco[nv][3]) };
        *(uint2*)&obase[nv * 16] = o2;
    }
}

// ---------------------------------------------------------------------------
extern "C" void kernel_launch(void* const* d_in, const int* in_sizes, int n_in,
                              void* d_out, int out_size, void* d_ws, size_t ws_size,
                              hipStream_t stream) {
    const float* q  = (const float*)d_in[0];
    const float* k  = (const float*)d_in[1];
    const float* v  = (const float*)d_in[2];
    const float* Wq = (const float*)d_in[3];
    const float* bq = (const float*)d_in[4];
    const float* Wk = (const float*)d_in[5];
    const float* bk = (const float*)d_in[6];
    const float* Wv = (const float*)d_in[7];
    const float* bv = (const float*)d_in[8];
    const float* Wo = (const float*)d_in[9];
    const float* bo = (const float*)d_in[10];

    float* out  = (float*)d_out;                    // [2,2048,1024]
    float* attn = out + (size_t)2 * 2048 * 1024;    // [2,16,2048,2048]

    const size_t HS = 4194304;                      // 2*16*2048*64
    unsigned short* qkvb = (unsigned short*)d_ws;   // 3*HS bf16
    unsigned short* WT   = qkvb + 3 * HS;           // 4 * 1M bf16 (transposed weights)
    unsigned short* Qh   = WT + 4 * 1048576;        // [B,H,L,64]
    unsigned short* Kh   = Qh + HS;                 // [B,H,L,64]
    unsigned short* Vt   = Kh + HS;                 // [B,H,64,L]
    unsigned short* Oh   = Vt + HS;                 // [B,L,1024]

    conv_wT  <<<dim3(16, 16, 4), 256, 0, stream>>>(Wq, Wk, Wv, Wo, WT);
    conv_bf16<<<dim3(2048, 3),  256, 0, stream>>>(q, k, v, qkvb);
    gemm_qkv <<<dim3(8, 32, 3), 256, 0, stream>>>(qkvb, WT, bq, bk, bv, Qh, Kh, Vt);
    attn_kernel<<<dim3(512), 512, 0, stream>>>(Qh, Kh, Vt, attn, Oh);
    gemm_o   <<<dim3(8, 32),   256, 0, stream>>>(Oh, WT + 3 * 1048576, bo, out);
}

// Round 3
// 314.214 us; speedup vs baseline: 1.6074x; 1.6074x over previous
//
#include <hip/hip_runtime.h>
#include <hip/hip_bf16.h>

typedef float f32x4 __attribute__((ext_vector_type(4)));
typedef short bf16x8 __attribute__((ext_vector_type(8)));

#define MFMA_BF16 __builtin_amdgcn_mfma_f32_16x16x32_bf16

static __device__ __forceinline__ unsigned short f2bf(float f) {
    __hip_bfloat16 h = __float2bfloat16(f);
    return __builtin_bit_cast(unsigned short, h);
}
static __device__ __forceinline__ unsigned int pack2(float a, float b) {
    return (unsigned int)f2bf(a) | ((unsigned int)f2bf(b) << 16);
}

// Async global->LDS, 16B per lane. LDS dest is wave-uniform base + lane*16.
static __device__ __forceinline__ void gl16(const unsigned short* g, unsigned short* l) {
    unsigned short* gg = const_cast<unsigned short*>(g);
    __builtin_amdgcn_global_load_lds(
        (__attribute__((address_space(1))) unsigned int*)gg,
        (__attribute__((address_space(3))) unsigned int*)l, 16, 0, 0);
}

// ---------------------------------------------------------------------------
// Prep 1: W [1024][1024] f32 (k-major) -> Wt [1024][1024] bf16 (n-major, k-contig)
// ---------------------------------------------------------------------------
__global__ __launch_bounds__(256) void conv_wT(
    const float* __restrict__ Wq, const float* __restrict__ Wk,
    const float* __restrict__ Wv, const float* __restrict__ Wo,
    unsigned short* __restrict__ WT)
{
    const int z = blockIdx.z;
    const float* W = (z == 0) ? Wq : (z == 1) ? Wk : (z == 2) ? Wv : Wo;
    unsigned short* Wt = WT + (size_t)z * 1048576;
    const int k0 = blockIdx.x * 64, n0 = blockIdx.y * 64;
    __shared__ float tl[64][68];
    const int t = threadIdx.x;
    const int r = t >> 2, cs = (t & 3) * 16;
#pragma unroll
    for (int j = 0; j < 4; j++)
        *(float4*)&tl[r][cs + j * 4] = *(const float4*)&W[(size_t)(k0 + r) * 1024 + n0 + cs + j * 4];
    __syncthreads();
    const int n = t & 63, kb = (t >> 6) * 16;
#pragma unroll
    for (int j = 0; j < 4; j++) {
        const int kk = kb + j * 4;
        uint2 o = { pack2(tl[kk][n], tl[kk + 1][n]), pack2(tl[kk + 2][n], tl[kk + 3][n]) };
        *(uint2*)&Wt[(size_t)(n0 + n) * 1024 + k0 + kk] = o;
    }
}

// ---------------------------------------------------------------------------
// Prep 2: q/k/v f32 -> bf16. grid (2048, 3).
// ---------------------------------------------------------------------------
__global__ __launch_bounds__(256) void conv_bf16(
    const float* __restrict__ q, const float* __restrict__ k, const float* __restrict__ v,
    unsigned short* __restrict__ qkvb)
{
    const int z = blockIdx.y;
    const float* s = (z == 0) ? q : (z == 1) ? k : v;
    unsigned short* d = qkvb + (size_t)z * 4194304;
    const size_t i = ((size_t)blockIdx.x * 256 + threadIdx.x) * 8;
    float4 a = *(const float4*)&s[i], b = *(const float4*)&s[i + 4];
    uint4 o = { pack2(a.x, a.y), pack2(a.z, a.w), pack2(b.x, b.y), pack2(b.z, b.w) };
    *(uint4*)&d[i] = o;
}

// ---------------------------------------------------------------------------
// Shared GEMM core: C(128x128) = A(row-major [M][1024] bf16) x Bt^T
// ---------------------------------------------------------------------------
static __device__ __forceinline__ void gemm_core(
    const unsigned short* __restrict__ A, const unsigned short* __restrict__ Bt,
    unsigned short* lA, unsigned short* lB, int m0, int n0, f32x4 (&acc)[4][4])
{
    const int t = threadIdx.x;
    const int w = t >> 6, lane = t & 63, lrow = lane & 15, lkg = lane >> 4;
    const int wr = w >> 1, wc = w & 1;
    const int srow = lane >> 2, sseg = (lane & 3) * 8;

    for (int k0 = 0; k0 < 1024; k0 += 32) {
        gl16(&A[(size_t)(m0 + w * 32 + srow) * 1024 + k0 + sseg], &lA[w * 1024]);
        gl16(&A[(size_t)(m0 + w * 32 + 16 + srow) * 1024 + k0 + sseg], &lA[w * 1024 + 512]);
        gl16(&Bt[(size_t)(n0 + w * 32 + srow) * 1024 + k0 + sseg], &lB[w * 1024]);
        gl16(&Bt[(size_t)(n0 + w * 32 + 16 + srow) * 1024 + k0 + sseg], &lB[w * 1024 + 512]);
        __syncthreads();
        bf16x8 af[4], bfr[4];
#pragma unroll
        for (int mi = 0; mi < 4; mi++)
            af[mi] = *(const bf16x8*)&lA[(wr * 64 + mi * 16 + lrow) * 32 + lkg * 8];
#pragma unroll
        for (int ni = 0; ni < 4; ni++)
            bfr[ni] = *(const bf16x8*)&lB[(wc * 64 + ni * 16 + lrow) * 32 + lkg * 8];
#pragma unroll
        for (int mi = 0; mi < 4; mi++)
#pragma unroll
            for (int ni = 0; ni < 4; ni++)
                acc[mi][ni] = MFMA_BF16(af[mi], bfr[ni], acc[mi][ni], 0, 0, 0);
        __syncthreads();
    }
}

// ---------------------------------------------------------------------------
// QKV projections. z=0: Q->[B,H,L,64]; z=1: K->[B,H,L,64]; z=2: V->[B,H,64,L].
// ---------------------------------------------------------------------------
__global__ __launch_bounds__(256) void gemm_qkv(
    const unsigned short* __restrict__ qkvb, const unsigned short* __restrict__ WT,
    const float* __restrict__ bq, const float* __restrict__ bk, const float* __restrict__ bv,
    unsigned short* __restrict__ Qh, unsigned short* __restrict__ Kh, unsigned short* __restrict__ Vt)
{
    const int z = blockIdx.z;
    const unsigned short* A = qkvb + (size_t)z * 4194304;
    const unsigned short* Bt = WT + (size_t)z * 1048576;
    const float* bias = (z == 0) ? bq : (z == 1) ? bk : bv;

    const int n0 = blockIdx.x * 128, m0 = blockIdx.y * 128;
    __shared__ unsigned short lA[4096], lB[4096];
    f32x4 acc[4][4];
#pragma unroll
    for (int i = 0; i < 4; i++)
#pragma unroll
        for (int j = 0; j < 4; j++) acc[i][j] = (f32x4){0.f, 0.f, 0.f, 0.f};

    gemm_core(A, Bt, lA, lB, m0, n0, acc);

    const int t = threadIdx.x;
    const int w = t >> 6, lane = t & 63, lrow = lane & 15, lkg = lane >> 4;
    const int wr = w >> 1, wc = w & 1;

#pragma unroll
    for (int mi = 0; mi < 4; mi++) {
#pragma unroll
        for (int ni = 0; ni < 4; ni++) {
            const int gn = n0 + wc * 64 + ni * 16 + lrow;
            const float bb = bias[gn];
            const int hh = gn >> 6, dk = gn & 63;
            const int gm0 = m0 + wr * 64 + mi * 16 + lkg * 4;
            const int b2 = gm0 >> 11, ll = gm0 & 2047;
            if (z < 2) {
                unsigned short* C = (z == 0) ? Qh : Kh;
#pragma unroll
                for (int r = 0; r < 4; r++)
                    C[(size_t)((b2 * 16 + hh) * 2048 + ll + r) * 64 + dk] = f2bf(acc[mi][ni][r] + bb);
            } else {
                uint2 o = { pack2(acc[mi][ni][0] + bb, acc[mi][ni][1] + bb),
                            pack2(acc[mi][ni][2] + bb, acc[mi][ni][3] + bb) };
                *(uint2*)&Vt[(size_t)((b2 * 16 + hh) * 64 + dk) * 2048 + ll] = o;
            }
        }
    }
}

// ---------------------------------------------------------------------------
// Output projection: out_f32 = Oh_bf16 @ WoT^T + bo.
// ---------------------------------------------------------------------------
__global__ __launch_bounds__(256) void gemm_o(
    const unsigned short* __restrict__ Oh, const unsigned short* __restrict__ WoT,
    const float* __restrict__ bo, float* __restrict__ out)
{
    const int n0 = blockIdx.x * 128, m0 = blockIdx.y * 128;
    __shared__ unsigned short lA[4096], lB[4096];
    f32x4 acc[4][4];
#pragma unroll
    for (int i = 0; i < 4; i++)
#pragma unroll
        for (int j = 0; j < 4; j++) acc[i][j] = (f32x4){0.f, 0.f, 0.f, 0.f};

    gemm_core(Oh, WoT, lA, lB, m0, n0, acc);

    const int t = threadIdx.x;
    const int w = t >> 6, lane = t & 63, lrow = lane & 15, lkg = lane >> 4;
    const int wr = w >> 1, wc = w & 1;

#pragma unroll
    for (int mi = 0; mi < 4; mi++) {
#pragma unroll
        for (int ni = 0; ni < 4; ni++) {
            const int gn = n0 + wc * 64 + ni * 16 + lrow;
            const float bb = bo[gn];
            const int gm0 = m0 + wr * 64 + mi * 16 + lkg * 4;
#pragma unroll
            for (int r = 0; r < 4; r++)
                out[(size_t)(gm0 + r) * 1024 + gn] = acc[mi][ni][r] + bb;
        }
    }
}

// ---------------------------------------------------------------------------
// Fused attention. 8 waves x 16 q-rows, Q-tile 128. K/V staged in LDS via
// global_load_lds with pre-swizzled source (linear dest + swizzled read).
// Swapped QK^T: S^T = MFMA(K, Q). Sweep 1: row sums (no max: |S| small).
// Sweep 2: recompute S, p = exp2(S*c - log2 l), nt-store attn, PV via
// wave-private swizzled lP and LDS V^T.
// ---------------------------------------------------------------------------
__global__ __launch_bounds__(512) void attn_kernel(
    const unsigned short* __restrict__ Qh, const unsigned short* __restrict__ Kh,
    const unsigned short* __restrict__ Vt, float* __restrict__ attn,
    unsigned short* __restrict__ Oh)
{
    const int bid = blockIdx.x;
    const int swz = (bid & 7) * 64 + (bid >> 3);     // XCD-contiguous
    const int bh = swz >> 4;
    const int q0 = (swz & 15) * 128;
    const int b = bh >> 4, h = bh & 15;
    const int t = threadIdx.x;
    const int w = t >> 6, lane = t & 63, ql = lane & 15, kg = lane >> 4;

    __shared__ unsigned short lK[8192];      // [128 k][8 col16], col16 ^= k&7
    __shared__ unsigned short lV[8192];      // [64 dv][16 col16], low3 ^= dv&7
    __shared__ unsigned short lP[8 * 2048];  // per-wave [16 q][128 k], swizzled

    const size_t kvbase = (size_t)bh * 2048 * 64;
    const float C = 0.18033688011112042f;    // 0.125 * log2(e)

    const unsigned short* qptr = Qh + kvbase + (size_t)(q0 + w * 16 + ql) * 64 + kg * 8;
    const bf16x8 qf0 = *(const bf16x8*)(qptr);
    const bf16x8 qf1 = *(const bf16x8*)(qptr + 32);

    const unsigned short* Kbh = Kh + kvbase;
    const unsigned short* Vbh = Vt + kvbase;

    // staging coordinates (pre-swizzled global source, linear LDS dest)
    const int kr = w * 8 + (lane >> 3);              // K row 0..63 (+64 on issue 2)
    const int kc = (lane & 7) ^ (kr & 7);            // source col16
    const int vr = w * 4 + (lane >> 4);              // V row 0..31 (+32 on issue 2)
    const int vc0 = lane & 15;
    const int vc = (vc0 & 8) | ((vc0 & 7) ^ (vr & 7));
    const int r7 = ql & 7;

    // ---- sweep 1: denominators ----
    f32x4 ls4 = (f32x4){0.f, 0.f, 0.f, 0.f};
    for (int kt = 0; kt < 16; ++kt) {
        const int k0 = kt * 128;
        gl16(Kbh + (size_t)(k0 + kr) * 64 + kc * 8, &lK[w * 512]);
        gl16(Kbh + (size_t)(k0 + kr + 64) * 64 + kc * 8, &lK[4096 + w * 512]);
        __syncthreads();
#pragma unroll
        for (int ni = 0; ni < 8; ni++) {
            const int rb = (ni * 16 + ql) * 64;
            bf16x8 kf0 = *(const bf16x8*)&lK[rb + ((kg ^ r7) * 8)];
            bf16x8 kf1 = *(const bf16x8*)&lK[rb + (((4 + kg) ^ r7) * 8)];
            f32x4 s = (f32x4){0.f, 0.f, 0.f, 0.f};
            s = MFMA_BF16(kf0, qf0, s, 0, 0, 0);
            s = MFMA_BF16(kf1, qf1, s, 0, 0, 0);
            f32x4 e;
#pragma unroll
            for (int r = 0; r < 4; r++) e[r] = exp2f(s[r] * C);
            ls4 += e;
        }
        __syncthreads();
    }
    float lsum = ls4[0] + ls4[1] + ls4[2] + ls4[3];
    lsum += __shfl_xor(lsum, 16);
    lsum += __shfl_xor(lsum, 32);
    const float mlg = -log2f(lsum);          // p = exp2(S*C - log2 l)

    // ---- sweep 2: attn write + PV ----
    f32x4 acco[4];
#pragma unroll
    for (int nv = 0; nv < 4; nv++) acco[nv] = (f32x4){0.f, 0.f, 0.f, 0.f};

    unsigned short* lPw = &lP[w * 2048];
    const int swz8 = r7 << 3;
    float* arow = attn + ((size_t)bh * 2048 + q0 + w * 16 + ql) * 2048;

    for (int kt = 0; kt < 16; ++kt) {
        const int k0 = kt * 128;
        gl16(Kbh + (size_t)(k0 + kr) * 64 + kc * 8, &lK[w * 512]);
        gl16(Kbh + (size_t)(k0 + kr + 64) * 64 + kc * 8, &lK[4096 + w * 512]);
        gl16(Vbh + (size_t)vr * 2048 + k0 + vc * 8, &lV[w * 512]);
        gl16(Vbh + (size_t)(vr + 32) * 2048 + k0 + vc * 8, &lV[4096 + w * 512]);
        __syncthreads();
#pragma unroll
        for (int ni = 0; ni < 8; ni++) {
            const int rb = (ni * 16 + ql) * 64;
            bf16x8 kf0 = *(const bf16x8*)&lK[rb + ((kg ^ r7) * 8)];
            bf16x8 kf1 = *(const bf16x8*)&lK[rb + (((4 + kg) ^ r7) * 8)];
            f32x4 s = (f32x4){0.f, 0.f, 0.f, 0.f};
            s = MFMA_BF16(kf0, qf0, s, 0, 0, 0);
            s = MFMA_BF16(kf1, qf1, s, 0, 0, 0);
            f32x4 p;
#pragma unroll
            for (int r = 0; r < 4; r++) p[r] = exp2f(fmaf(s[r], C, mlg));
            uint2 pk = { pack2(p[0], p[1]), pack2(p[2], p[3]) };
            *(uint2*)&lPw[(ql * 128 + ni * 16 + kg * 4) ^ swz8] = pk;
            __builtin_nontemporal_store(p, (f32x4*)&arow[k0 + ni * 16 + kg * 4]);
        }
        // PV: O^T += V^T x P^T
#pragma unroll
        for (int s4 = 0; s4 < 4; s4++) {
            bf16x8 pf = *(const bf16x8*)&lPw[(ql * 128 + s4 * 32 + kg * 8) ^ swz8];
#pragma unroll
            for (int nv = 0; nv < 4; nv++) {
                const int c = s4 * 4 + kg;
                const int cc = (c & 8) | ((c & 7) ^ r7);
                bf16x8 vf = *(const bf16x8*)&lV[(nv * 16 + ql) * 128 + cc * 8];
                acco[nv] = MFMA_BF16(vf, pf, acco[nv], 0, 0, 0);
            }
        }
        __syncthreads();
    }

    unsigned short* obase = Oh + ((size_t)(b * 2048 + q0 + w * 16 + ql)) * 1024 + h * 64 + kg * 4;
#pragma unroll
    for (int nv = 0; nv < 4; nv++) {
        uint2 o2 = { pack2(acco[nv][0], acco[nv][1]), pack2(acco[nv][2], acco[nv][3]) };
        *(uint2*)&obase[nv * 16] = o2;
    }
}

// ---------------------------------------------------------------------------
extern "C" void kernel_launch(void* const* d_in, const int* in_sizes, int n_in,
                              void* d_out, int out_size, void* d_ws, size_t ws_size,
                              hipStream_t stream) {
    const float* q  = (const float*)d_in[0];
    const float* k  = (const float*)d_in[1];
    const float* v  = (const float*)d_in[2];
    const float* Wq = (const float*)d_in[3];
    const float* bq = (const float*)d_in[4];
    const float* Wk = (const float*)d_in[5];
    const float* bk = (const float*)d_in[6];
    const float* Wv = (const float*)d_in[7];
    const float* bv = (const float*)d_in[8];
    const float* Wo = (const float*)d_in[9];
    const float* bo = (const float*)d_in[10];

    float* out  = (float*)d_out;                    // [2,2048,1024]
    float* attn = out + (size_t)2 * 2048 * 1024;    // [2,16,2048,2048]

    const size_t HS = 4194304;                      // 2*16*2048*64
    unsigned short* qkvb = (unsigned short*)d_ws;   // 3*HS bf16
    unsigned short* WT   = qkvb + 3 * HS;           // 4 * 1M bf16
    unsigned short* Qh   = WT + 4 * 1048576;        // [B,H,L,64]
    unsigned short* Kh   = Qh + HS;                 // [B,H,L,64]
    unsigned short* Vt   = Kh + HS;                 // [B,H,64,L]
    unsigned short* Oh   = Vt + HS;                 // [B,L,1024]

    conv_wT  <<<dim3(16, 16, 4), 256, 0, stream>>>(Wq, Wk, Wv, Wo, WT);
    conv_bf16<<<dim3(2048, 3),  256, 0, stream>>>(q, k, v, qkvb);
    gemm_qkv <<<dim3(8, 32, 3), 256, 0, stream>>>(qkvb, WT, bq, bk, bv, Qh, Kh, Vt);
    attn_kernel<<<dim3(512), 512, 0, stream>>>(Qh, Kh, Vt, attn, Oh);
    gemm_o   <<<dim3(8, 32),   256, 0, stream>>>(Oh, WT + 3 * 1048576, bo, out);
}

// Round 4
// 300.639 us; speedup vs baseline: 1.6799x; 1.0452x over previous
//
#include <hip/hip_runtime.h>
#include <hip/hip_bf16.h>

typedef float f32x4 __attribute__((ext_vector_type(4)));
typedef short bf16x8 __attribute__((ext_vector_type(8)));

#define MFMA_BF16 __builtin_amdgcn_mfma_f32_16x16x32_bf16

static __device__ __forceinline__ unsigned short f2bf(float f) {
    __hip_bfloat16 h = __float2bfloat16(f);
    return __builtin_bit_cast(unsigned short, h);
}
static __device__ __forceinline__ unsigned int pack2(float a, float b) {
    return (unsigned int)f2bf(a) | ((unsigned int)f2bf(b) << 16);
}

// Async global->LDS, 16B per lane. LDS dest is wave-uniform base + lane*16.
static __device__ __forceinline__ void gl16(const unsigned short* g, unsigned short* l) {
    unsigned short* gg = const_cast<unsigned short*>(g);
    __builtin_amdgcn_global_load_lds(
        (__attribute__((address_space(1))) unsigned int*)gg,
        (__attribute__((address_space(3))) unsigned int*)l, 16, 0, 0);
}

// ---------------------------------------------------------------------------
// Prep 1: W [1024][1024] f32 (k-major) -> Wt [1024][1024] bf16 (n-major, k-contig)
// ---------------------------------------------------------------------------
__global__ __launch_bounds__(256) void conv_wT(
    const float* __restrict__ Wq, const float* __restrict__ Wk,
    const float* __restrict__ Wv, const float* __restrict__ Wo,
    unsigned short* __restrict__ WT)
{
    const int z = blockIdx.z;
    const float* W = (z == 0) ? Wq : (z == 1) ? Wk : (z == 2) ? Wv : Wo;
    unsigned short* Wt = WT + (size_t)z * 1048576;
    const int k0 = blockIdx.x * 64, n0 = blockIdx.y * 64;
    __shared__ float tl[64][68];
    const int t = threadIdx.x;
    const int r = t >> 2, cs = (t & 3) * 16;
#pragma unroll
    for (int j = 0; j < 4; j++)
        *(float4*)&tl[r][cs + j * 4] = *(const float4*)&W[(size_t)(k0 + r) * 1024 + n0 + cs + j * 4];
    __syncthreads();
    const int n = t & 63, kb = (t >> 6) * 16;
#pragma unroll
    for (int j = 0; j < 4; j++) {
        const int kk = kb + j * 4;
        uint2 o = { pack2(tl[kk][n], tl[kk + 1][n]), pack2(tl[kk + 2][n], tl[kk + 3][n]) };
        *(uint2*)&Wt[(size_t)(n0 + n) * 1024 + k0 + kk] = o;
    }
}

// ---------------------------------------------------------------------------
// Prep 2: q/k/v f32 -> bf16. grid (2048, 3).
// ---------------------------------------------------------------------------
__global__ __launch_bounds__(256) void conv_bf16(
    const float* __restrict__ q, const float* __restrict__ k, const float* __restrict__ v,
    unsigned short* __restrict__ qkvb)
{
    const int z = blockIdx.y;
    const float* s = (z == 0) ? q : (z == 1) ? k : v;
    unsigned short* d = qkvb + (size_t)z * 4194304;
    const size_t i = ((size_t)blockIdx.x * 256 + threadIdx.x) * 8;
    float4 a = *(const float4*)&s[i], b = *(const float4*)&s[i + 4];
    uint4 o = { pack2(a.x, a.y), pack2(a.z, a.w), pack2(b.x, b.y), pack2(b.z, b.w) };
    *(uint4*)&d[i] = o;
}

// ---------------------------------------------------------------------------
// Shared GEMM core: C(128x128) = A(row-major [M][1024] bf16) x Bt^T
// ---------------------------------------------------------------------------
static __device__ __forceinline__ void gemm_core(
    const unsigned short* __restrict__ A, const unsigned short* __restrict__ Bt,
    unsigned short* lA, unsigned short* lB, int m0, int n0, f32x4 (&acc)[4][4])
{
    const int t = threadIdx.x;
    const int w = t >> 6, lane = t & 63, lrow = lane & 15, lkg = lane >> 4;
    const int wr = w >> 1, wc = w & 1;
    const int srow = lane >> 2, sseg = (lane & 3) * 8;

    for (int k0 = 0; k0 < 1024; k0 += 32) {
        gl16(&A[(size_t)(m0 + w * 32 + srow) * 1024 + k0 + sseg], &lA[w * 1024]);
        gl16(&A[(size_t)(m0 + w * 32 + 16 + srow) * 1024 + k0 + sseg], &lA[w * 1024 + 512]);
        gl16(&Bt[(size_t)(n0 + w * 32 + srow) * 1024 + k0 + sseg], &lB[w * 1024]);
        gl16(&Bt[(size_t)(n0 + w * 32 + 16 + srow) * 1024 + k0 + sseg], &lB[w * 1024 + 512]);
        __syncthreads();
        bf16x8 af[4], bfr[4];
#pragma unroll
        for (int mi = 0; mi < 4; mi++)
            af[mi] = *(const bf16x8*)&lA[(wr * 64 + mi * 16 + lrow) * 32 + lkg * 8];
#pragma unroll
        for (int ni = 0; ni < 4; ni++)
            bfr[ni] = *(const bf16x8*)&lB[(wc * 64 + ni * 16 + lrow) * 32 + lkg * 8];
#pragma unroll
        for (int mi = 0; mi < 4; mi++)
#pragma unroll
            for (int ni = 0; ni < 4; ni++)
                acc[mi][ni] = MFMA_BF16(af[mi], bfr[ni], acc[mi][ni], 0, 0, 0);
        __syncthreads();
    }
}

// ---------------------------------------------------------------------------
// QKV projections. z=0: Q->[B,H,L,64]; z=1: K->[B,H,L,64]; z=2: V->[B,H,64,L].
// ---------------------------------------------------------------------------
__global__ __launch_bounds__(256) void gemm_qkv(
    const unsigned short* __restrict__ qkvb, const unsigned short* __restrict__ WT,
    const float* __restrict__ bq, const float* __restrict__ bk, const float* __restrict__ bv,
    unsigned short* __restrict__ Qh, unsigned short* __restrict__ Kh, unsigned short* __restrict__ Vt)
{
    const int z = blockIdx.z;
    const unsigned short* A = qkvb + (size_t)z * 4194304;
    const unsigned short* Bt = WT + (size_t)z * 1048576;
    const float* bias = (z == 0) ? bq : (z == 1) ? bk : bv;

    const int n0 = blockIdx.x * 128, m0 = blockIdx.y * 128;
    __shared__ unsigned short lA[4096], lB[4096];
    f32x4 acc[4][4];
#pragma unroll
    for (int i = 0; i < 4; i++)
#pragma unroll
        for (int j = 0; j < 4; j++) acc[i][j] = (f32x4){0.f, 0.f, 0.f, 0.f};

    gemm_core(A, Bt, lA, lB, m0, n0, acc);

    const int t = threadIdx.x;
    const int w = t >> 6, lane = t & 63, lrow = lane & 15, lkg = lane >> 4;
    const int wr = w >> 1, wc = w & 1;

#pragma unroll
    for (int mi = 0; mi < 4; mi++) {
#pragma unroll
        for (int ni = 0; ni < 4; ni++) {
            const int gn = n0 + wc * 64 + ni * 16 + lrow;
            const float bb = bias[gn];
            const int hh = gn >> 6, dk = gn & 63;
            const int gm0 = m0 + wr * 64 + mi * 16 + lkg * 4;
            const int b2 = gm0 >> 11, ll = gm0 & 2047;
            if (z < 2) {
                unsigned short* C = (z == 0) ? Qh : Kh;
#pragma unroll
                for (int r = 0; r < 4; r++)
                    C[(size_t)((b2 * 16 + hh) * 2048 + ll + r) * 64 + dk] = f2bf(acc[mi][ni][r] + bb);
            } else {
                uint2 o = { pack2(acc[mi][ni][0] + bb, acc[mi][ni][1] + bb),
                            pack2(acc[mi][ni][2] + bb, acc[mi][ni][3] + bb) };
                *(uint2*)&Vt[(size_t)((b2 * 16 + hh) * 64 + dk) * 2048 + ll] = o;
            }
        }
    }
}

// ---------------------------------------------------------------------------
// Output projection: out_f32 = Oh_bf16 @ WoT^T + bo.
// ---------------------------------------------------------------------------
__global__ __launch_bounds__(256) void gemm_o(
    const unsigned short* __restrict__ Oh, const unsigned short* __restrict__ WoT,
    const float* __restrict__ bo, float* __restrict__ out)
{
    const int n0 = blockIdx.x * 128, m0 = blockIdx.y * 128;
    __shared__ unsigned short lA[4096], lB[4096];
    f32x4 acc[4][4];
#pragma unroll
    for (int i = 0; i < 4; i++)
#pragma unroll
        for (int j = 0; j < 4; j++) acc[i][j] = (f32x4){0.f, 0.f, 0.f, 0.f};

    gemm_core(Oh, WoT, lA, lB, m0, n0, acc);

    const int t = threadIdx.x;
    const int w = t >> 6, lane = t & 63, lrow = lane & 15, lkg = lane >> 4;
    const int wr = w >> 1, wc = w & 1;

#pragma unroll
    for (int mi = 0; mi < 4; mi++) {
#pragma unroll
        for (int ni = 0; ni < 4; ni++) {
            const int gn = n0 + wc * 64 + ni * 16 + lrow;
            const float bb = bo[gn];
            const int gm0 = m0 + wr * 64 + mi * 16 + lkg * 4;
#pragma unroll
            for (int r = 0; r < 4; r++)
                out[(size_t)(gm0 + r) * 1024 + gn] = acc[mi][ni][r] + bb;
        }
    }
}

// ---------------------------------------------------------------------------
// Fused attention, 2-phase double-buffered (T3-minimum schedule).
// 8 waves x 16 q-rows (Q-tile 128). Sweep 1: KVBLK=128 K-only tiles, row sums.
// Sweep 2: KVBLK=64 K+V tiles; p = exp2(S*C - log2 l); nt-store attn; PV via
// wave-private swizzled lP. Stage(t+1) issued BEFORE compute(t); ONE barrier
// per tile (its implicit vmcnt(0) drain is covered by the compute phase).
// LDS: 2x16KB KV buffers + 16KB lP = 48KB -> 2 blocks/CU.
// ---------------------------------------------------------------------------
__global__ __launch_bounds__(512, 4) void attn_kernel(
    const unsigned short* __restrict__ Qh, const unsigned short* __restrict__ Kh,
    const unsigned short* __restrict__ Vt, float* __restrict__ attn,
    unsigned short* __restrict__ Oh)
{
    const int bid = blockIdx.x;
    const int swz = (bid & 7) * 64 + (bid >> 3);     // XCD-contiguous
    const int bh = swz >> 4;
    const int q0 = (swz & 15) * 128;
    const int b = bh >> 4, h = bh & 15;
    const int t = threadIdx.x;
    const int w = t >> 6, lane = t & 63, ql = lane & 15, kg = lane >> 4;

    __shared__ unsigned short lS[2][8192];   // dbuf: s1: K[128][8 slots]; s2: K[64][8] + V[64][8]
    __shared__ unsigned short lP[8192];      // per-wave [16 q][64 k], swizzled

    const size_t kvbase = (size_t)bh * 2048 * 64;
    const float C = 0.18033688011112042f;    // 0.125 * log2(e)

    const unsigned short* qptr = Qh + kvbase + (size_t)(q0 + w * 16 + ql) * 64 + kg * 8;
    const bf16x8 qf0 = *(const bf16x8*)(qptr);
    const bf16x8 qf1 = *(const bf16x8*)(qptr + 32);

    const unsigned short* Kbh = Kh + kvbase;
    const unsigned short* Vbh = Vt + kvbase;

    // staging coords: wave w covers rows w*8..w*8+7; source col16 pre-swizzled
    const int kr = w * 8 + (lane >> 3);
    const int kc = (lane & 7) ^ (kr & 7);
    const int r7 = ql & 7;

    // ---- sweep 1: denominators (K tiles of 128 rows, double-buffered) ----
    f32x4 ls4 = (f32x4){0.f, 0.f, 0.f, 0.f};
    {
        gl16(Kbh + (size_t)kr * 64 + kc * 8, &lS[0][w * 512]);
        gl16(Kbh + (size_t)(kr + 64) * 64 + kc * 8, &lS[0][4096 + w * 512]);
        __syncthreads();
        int c = 0;
        for (int kt = 0; kt < 16; ++kt) {
            if (kt < 15) {
                const int k0n = (kt + 1) * 128;
                gl16(Kbh + (size_t)(k0n + kr) * 64 + kc * 8, &lS[c ^ 1][w * 512]);
                gl16(Kbh + (size_t)(k0n + kr + 64) * 64 + kc * 8, &lS[c ^ 1][4096 + w * 512]);
            }
            const unsigned short* Kl = lS[c];
#pragma unroll
            for (int ni = 0; ni < 8; ni++) {
                const int rb = (ni * 16 + ql) * 64;
                bf16x8 kf0 = *(const bf16x8*)&Kl[rb + ((kg ^ r7) * 8)];
                bf16x8 kf1 = *(const bf16x8*)&Kl[rb + (((4 + kg) ^ r7) * 8)];
                __builtin_amdgcn_s_setprio(1);
                f32x4 s = (f32x4){0.f, 0.f, 0.f, 0.f};
                s = MFMA_BF16(kf0, qf0, s, 0, 0, 0);
                s = MFMA_BF16(kf1, qf1, s, 0, 0, 0);
                __builtin_amdgcn_s_setprio(0);
#pragma unroll
                for (int r = 0; r < 4; r++) ls4[r] += exp2f(s[r] * C);
            }
            __syncthreads();
            c ^= 1;
        }
    }
    float lsum = ls4[0] + ls4[1] + ls4[2] + ls4[3];
    lsum += __shfl_xor(lsum, 16);
    lsum += __shfl_xor(lsum, 32);
    const float mlg = -log2f(lsum);          // p = exp2(S*C - log2 l)

    // ---- sweep 2: attn write + PV (K+V tiles of 64, double-buffered) ----
    f32x4 acco[4];
#pragma unroll
    for (int nv = 0; nv < 4; nv++) acco[nv] = (f32x4){0.f, 0.f, 0.f, 0.f};

    unsigned short* lPw = &lP[w * 1024];
    const int swz8 = r7 << 3;
    float* arow = attn + ((size_t)bh * 2048 + q0 + w * 16 + ql) * 2048;

    {
        gl16(Kbh + (size_t)kr * 64 + kc * 8, &lS[0][w * 512]);
        gl16(Vbh + (size_t)kr * 2048 + kc * 8, &lS[0][4096 + w * 512]);
        __syncthreads();
        int c = 0;
        for (int kt = 0; kt < 32; ++kt) {
            if (kt < 31) {
                const int k0n = (kt + 1) * 64;
                gl16(Kbh + (size_t)(k0n + kr) * 64 + kc * 8, &lS[c ^ 1][w * 512]);
                gl16(Vbh + (size_t)kr * 2048 + k0n + kc * 8, &lS[c ^ 1][4096 + w * 512]);
            }
            const int k0 = kt * 64;
            const unsigned short* Kl = lS[c];
            const unsigned short* Vl = &lS[c][4096];

            f32x4 sacc[4];
            __builtin_amdgcn_s_setprio(1);
#pragma unroll
            for (int ni = 0; ni < 4; ni++) {
                const int rb = (ni * 16 + ql) * 64;
                bf16x8 kf0 = *(const bf16x8*)&Kl[rb + ((kg ^ r7) * 8)];
                bf16x8 kf1 = *(const bf16x8*)&Kl[rb + (((4 + kg) ^ r7) * 8)];
                f32x4 s = (f32x4){0.f, 0.f, 0.f, 0.f};
                s = MFMA_BF16(kf0, qf0, s, 0, 0, 0);
                sacc[ni] = MFMA_BF16(kf1, qf1, s, 0, 0, 0);
            }
            __builtin_amdgcn_s_setprio(0);
#pragma unroll
            for (int ni = 0; ni < 4; ni++) {
                f32x4 p;
#pragma unroll
                for (int r = 0; r < 4; r++) p[r] = exp2f(fmaf(sacc[ni][r], C, mlg));
                uint2 pk = { pack2(p[0], p[1]), pack2(p[2], p[3]) };
                *(uint2*)&lPw[(ql * 64 + ni * 16 + kg * 4) ^ swz8] = pk;
                __builtin_nontemporal_store(p, (f32x4*)&arow[k0 + ni * 16 + kg * 4]);
            }
            // PV: O^T += V^T x P^T
            __builtin_amdgcn_s_setprio(1);
#pragma unroll
            for (int s4 = 0; s4 < 2; s4++) {
                bf16x8 pf = *(const bf16x8*)&lPw[(ql * 64 + s4 * 32 + kg * 8) ^ swz8];
#pragma unroll
                for (int nv = 0; nv < 4; nv++) {
                    const int cc = (s4 * 4 + kg) ^ r7;
                    bf16x8 vf = *(const bf16x8*)&Vl[(nv * 16 + ql) * 64 + cc * 8];
                    acco[nv] = MFMA_BF16(vf, pf, acco[nv], 0, 0, 0);
                }
            }
            __builtin_amdgcn_s_setprio(0);
            __syncthreads();
            c ^= 1;
        }
    }

    unsigned short* obase = Oh + ((size_t)(b * 2048 + q0 + w * 16 + ql)) * 1024 + h * 64 + kg * 4;
#pragma unroll
    for (int nv = 0; nv < 4; nv++) {
        uint2 o2 = { pack2(acco[nv][0], acco[nv][1]), pack2(acco[nv][2], acco[nv][3]) };
        *(uint2*)&obase[nv * 16] = o2;
    }
}

// ---------------------------------------------------------------------------
extern "C" void kernel_launch(void* const* d_in, const int* in_sizes, int n_in,
                              void* d_out, int out_size, void* d_ws, size_t ws_size,
                              hipStream_t stream) {
    const float* q  = (const float*)d_in[0];
    const float* k  = (const float*)d_in[1];
    const float* v  = (const float*)d_in[2];
    const float* Wq = (const float*)d_in[3];
    const float* bq = (const float*)d_in[4];
    const float* Wk = (const float*)d_in[5];
    const float* bk = (const float*)d_in[6];
    const float* Wv = (const float*)d_in[7];
    const float* bv = (const float*)d_in[8];
    const float* Wo = (const float*)d_in[9];
    const float* bo = (const float*)d_in[10];

    float* out  = (float*)d_out;                    // [2,2048,1024]
    float* attn = out + (size_t)2 * 2048 * 1024;    // [2,16,2048,2048]

    const size_t HS = 4194304;                      // 2*16*2048*64
    unsigned short* qkvb = (unsigned short*)d_ws;   // 3*HS bf16
    unsigned short* WT   = qkvb + 3 * HS;           // 4 * 1M bf16
    unsigned short* Qh   = WT + 4 * 1048576;        // [B,H,L,64]
    unsigned short* Kh   = Qh + HS;                 // [B,H,L,64]
    unsigned short* Vt   = Kh + HS;                 // [B,H,64,L]
    unsigned short* Oh   = Vt + HS;                 // [B,L,1024]

    conv_wT  <<<dim3(16, 16, 4), 256, 0, stream>>>(Wq, Wk, Wv, Wo, WT);
    conv_bf16<<<dim3(2048, 3),  256, 0, stream>>>(q, k, v, qkvb);
    gemm_qkv <<<dim3(8, 32, 3), 256, 0, stream>>>(qkvb, WT, bq, bk, bv, Qh, Kh, Vt);
    attn_kernel<<<dim3(512), 512, 0, stream>>>(Qh, Kh, Vt, attn, Oh);
    gemm_o   <<<dim3(8, 32),   256, 0, stream>>>(Oh, WT + 3 * 1048576, bo, out);
}